// Round 10
// baseline (913.141 us; speedup 1.0000x reference)
//
#include <hip/hip_runtime.h>
#include <hip/hip_bf16.h>
#include <stdint.h>

#define F_DIM 512
#define C_DIM 512
#define K3    1536   // 3 * F_DIM
#define NTT   144    // K' tiles: 3 segments * 48 tiles (BK=32)
#define BKT   32

typedef _Float16 f16x8 __attribute__((ext_vector_type(8)));
typedef float    f32x4 __attribute__((ext_vector_type(4)));

__device__ __forceinline__ float rho_of(int p, int sb) {
    int d = sb - 1; if (d < 1) d = 1;
    return (float)(p - 1) / (float)d;
}

// 2-way fp16 split with exact pow2 plane scaling: v ~= h + m*2^-11
__device__ __forceinline__ void split2s(float v, _Float16& h, _Float16& m) {
    h = (_Float16)v;
    float r1 = v - (float)h;          // exact
    m = (_Float16)(r1 * 2048.0f);     // scale exact, one rounding
}

// ---------------- CSR build ----------------
__global__ void k_count(const int* __restrict__ parent, int* __restrict__ counts, int n) {
    int c = blockIdx.x * 256 + threadIdx.x;
    if (c >= 1 && c < n) atomicAdd(&counts[parent[c]], 1);
}

__device__ __forceinline__ int blockScanIncl(int v, int* sm) {
    int lane = threadIdx.x & 63;
    int w = threadIdx.x >> 6;
    #pragma unroll
    for (int d = 1; d < 64; d <<= 1) {
        int t = __shfl_up(v, d, 64);
        if (lane >= d) v += t;
    }
    if (lane == 63) sm[w] = v;
    __syncthreads();
    if (threadIdx.x < 64) {
        int s = (threadIdx.x < 16) ? sm[threadIdx.x] : 0;
        #pragma unroll
        for (int d = 1; d < 16; d <<= 1) {
            int t = __shfl_up(s, d, 64);
            if (lane >= d) s += t;
        }
        if (threadIdx.x < 16) sm[threadIdx.x] = s;
    }
    __syncthreads();
    return v + (w > 0 ? sm[w - 1] : 0);
}

__global__ void k_scan1(const int* __restrict__ counts, int* __restrict__ starts,
                        int* __restrict__ bsums, int n) {
    __shared__ int sm[16];
    int i = blockIdx.x * 1024 + threadIdx.x;
    int v = (i < n) ? counts[i] : 0;
    int incl = blockScanIncl(v, sm);
    if (i < n) starts[i] = incl - v;
    if (threadIdx.x == 1023) bsums[blockIdx.x] = incl;
}

__global__ void k_scan2(int* __restrict__ bsums, int nb) {
    __shared__ int sm[16];
    int v = ((int)threadIdx.x < nb) ? bsums[threadIdx.x] : 0;
    int incl = blockScanIncl(v, sm);
    if ((int)threadIdx.x < nb) bsums[threadIdx.x] = incl - v;  // exclusive
}

__global__ void k_scan3(int* __restrict__ starts, const int* __restrict__ bsums, int n) {
    int i = blockIdx.x * 1024 + threadIdx.x;
    if (i < n) starts[i] += bsums[blockIdx.x];
}

__global__ void k_fill(const int* __restrict__ parent, const int* __restrict__ pos,
                       const int* __restrict__ starts, int* __restrict__ childlist, int n) {
    int c = blockIdx.x * 256 + threadIdx.x;
    if (c >= 1 && c < n) childlist[starts[parent[c]] + pos[c]] = c;
}

// ---------------- B concat + 2-way split:  B[j][sec*512+f], sec: 0=Wt 1=Wl 2=Wr
__global__ void k_bcat(const float* __restrict__ Wt, const float* __restrict__ Wl,
                       const float* __restrict__ Wr,
                       _Float16* __restrict__ Bh, _Float16* __restrict__ Bm) {
    int i = blockIdx.x * 256 + threadIdx.x;
    if (i >= C_DIM * K3) return;
    int j = i / K3, kk = i - j * K3;
    int sec = kk >> 9, f = kk & 511;
    const float* W = (sec == 0) ? Wt : ((sec == 1) ? Wl : Wr);
    float v = W[j * F_DIM + f];
    _Float16 h, m;
    split2s(v, h, m);
    Bh[i] = h; Bm[i] = m;
}

// ---------------- aggregation: one wave per node.
__global__ __launch_bounds__(256)
void k_agg(const float* __restrict__ x, const int* __restrict__ level,
           const int* __restrict__ pos, const int* __restrict__ sib,
           const int* __restrict__ starts, const int* __restrict__ counts,
           const int* __restrict__ childlist,
           _Float16* __restrict__ Ah, _Float16* __restrict__ Am,
           int node0, int cnt) {
    int lane = threadIdx.x & 63;
    int gw = (blockIdx.x * 256 + threadIdx.x) >> 6;
    int nW = (gridDim.x * 256) >> 6;
    for (int i = gw; i < cnt; i += nW) {
        int s = node0 + i;
        float t = 0.5f * (float)level[s];
        float u = 1.0f - t;
        float u2 = u * u;
        float s0[8], s1[8];
        #pragma unroll
        for (int j = 0; j < 8; ++j) { s0[j] = 0.f; s1[j] = 0.f; }
        {
            float r = rho_of(pos[s], sib[s]);
            const float4* xp = (const float4*)(x + (size_t)s * F_DIM) + lane * 2;
            float4 a = xp[0], b = xp[1];
            float vv[8] = {a.x, a.y, a.z, a.w, b.x, b.y, b.z, b.w};
            #pragma unroll
            for (int j = 0; j < 8; ++j) { s0[j] += vv[j]; s1[j] = fmaf(r, vv[j], s1[j]); }
        }
        int cs = starts[s], ne = counts[s];
        for (int e = 0; e < ne; ++e) {
            int c = childlist[cs + e];
            float r = rho_of(pos[c], sib[c]);
            const float4* xp = (const float4*)(x + (size_t)c * F_DIM) + lane * 2;
            float4 a = xp[0], b = xp[1];
            float vv[8] = {a.x, a.y, a.z, a.w, b.x, b.y, b.z, b.w};
            #pragma unroll
            for (int j = 0; j < 8; ++j) { s0[j] += vv[j]; s1[j] = fmaf(r, vv[j], s1[j]); }
        }
        f16x8 ph[3], pm[3];
        #pragma unroll
        for (int j = 0; j < 8; ++j) {
            float a0 = t * s0[j];
            float a1 = fmaf(-u2, s1[j], u * s0[j]);
            float a2 = u * s1[j];
            _Float16 h, m;
            split2s(a0, h, m); ph[0][j] = h; pm[0][j] = m;
            split2s(a1, h, m); ph[1][j] = h; pm[1][j] = m;
            split2s(a2, h, m); ph[2][j] = h; pm[2][j] = m;
        }
        size_t rb = (size_t)i * K3 + (size_t)(lane * 8);
        #pragma unroll
        for (int sec = 0; sec < 3; ++sec) {
            *(f16x8*)(Ah + rb + sec * 512) = ph[sec];
            *(f16x8*)(Am + rb + sec * 512) = pm[sec];
        }
    }
}

// ---------------- GEMM: out = tanh(A(M x 1536) * Bcat^T + (1+nc)*bias)
// Single-accumulator flat K'=4608 schedule over plane-pair segments:
//   tiles [0,48):  Am x Bh   (cross term 2)
//   tiles [48,96): Ah x Bm   (cross term 1; Ah then stays L2-hot for seg 2)
//   T==96: acc *= 2^-11 (exact pow2 rescale of the cross sum, one-time VALU)
//   tiles [96,144): Ah x Bh  (main product accumulates on top)
// Geometry: BM=256, BN=256, BK=32; 512 thr = 8 waves (2Mx4N), wave 128x64;
// acc = 32 f32x4 (128 AGPR) + ~90 VGPR -> 2 waves/SIMD.
// Pipeline: 3-slot LDS ring (3 x (A16KB+B16KB) = 96KB), 2-tile lookahead,
// per tile: {8 ds_read | issue 2 gload_lds | 16 MFMA setprio} x2 phases,
// steady-state s_waitcnt vmcnt(4) (NEVER 0) + one raw s_barrier per tile.
// Ring safety: slot(T+2) == slot(T-1), whose reads ended at the T-1 barrier.
// BK=32 swizzle (R8 HW-verified, 0 conflicts): slot' = slot ^ ((row>>1)&3),
// inverse on global SOURCE (linear LDS dest), same XOR on ds_read address.
__device__ __forceinline__ f32x4 mfma16(f16x8 a, f16x8 b, f32x4 c) {
    return __builtin_amdgcn_mfma_f32_16x16x32_f16(a, b, c, 0, 0, 0);
}

#define AS1 __attribute__((address_space(1)))
#define AS3 __attribute__((address_space(3)))

__global__ __launch_bounds__(512, 2)
void k_gemm(const _Float16* __restrict__ Ah, const _Float16* __restrict__ Am,
            const _Float16* __restrict__ Bh, const _Float16* __restrict__ Bm,
            const float* __restrict__ bias, const int* __restrict__ counts,
            float* __restrict__ out, int Mreal, int row0) {
    __shared__ __align__(16) _Float16 sA[3][256 * 32];
    __shared__ __align__(16) _Float16 sB[3][256 * 32];

    // bijective XCD swizzle (m204); 2 col-tiles of an M-panel share an XCD
    int nwg = gridDim.x, bid = blockIdx.x;
    int q = nwg >> 3, r = nwg & 7;
    int xcd = bid & 7, idx = bid >> 3;
    int wg = (xcd < r ? xcd * (q + 1) : r * (q + 1) + (xcd - r) * q) + idx;
    int panel = wg >> 1, colt = wg & 1;
    int m0 = panel * 256, n0 = colt * 256;

    int tid = threadIdx.x;
    int lane = tid & 63, wid = tid >> 6;
    int wm = wid >> 2, wn = wid & 3;            // 2 x 4 waves
    int l15 = lane & 15, lg = lane >> 4;

    const char* gAh = (const char*)(Ah + (size_t)m0 * K3);
    const char* gAm = (const char*)(Am + (size_t)m0 * K3);
    const char* gBh = (const char*)(Bh + (size_t)n0 * K3);
    const char* gBm = (const char*)(Bm + (size_t)n0 * K3);

    // staging source offsets: chunk = half*512 + tid; row=chunk>>2; slot=chunk&3
    int ch0 = tid, ch1 = 512 + tid;
    int r0 = ch0 >> 2, s0 = (ch0 & 3) ^ ((r0 >> 1) & 3);
    int r1 = ch1 >> 2, s1 = (ch1 & 3) ^ ((r1 >> 1) & 3);
    int go0 = r0 * (K3 * 2) + (s0 << 4);
    int go1 = r1 * (K3 * 2) + (s1 << 4);
    // linear LDS dest (wave-uniform base; HW adds lane*16B)
    int ldo0 = (0 * 512 + wid * 64) * 8;
    int ldo1 = (1 * 512 + wid * 64) * 8;

    // ds_read swizzled k-slot (element offset): (row>>1)&3 == (l15>>1)&3
    int kswz = (lg ^ ((l15 >> 1) & 3)) << 3;

    f32x4 acc[8][4] = {};

#define ISSUE_A(tt)                                                                        \
    do {                                                                                   \
        int sg_ = (tt) >= 96 ? 2 : ((tt) >= 48 ? 1 : 0);                                   \
        int kb_ = ((tt) - sg_ * 48) * (BKT * 2);                                           \
        const char* ab_ = (sg_ == 0) ? gAm : gAh;                                          \
        int sl_ = (tt) % 3;                                                                \
        __builtin_amdgcn_global_load_lds((const AS1 unsigned int*)(ab_ + go0 + kb_),       \
            (AS3 unsigned int*)(&sA[sl_][ldo0]), 16, 0, 0);                                \
        __builtin_amdgcn_global_load_lds((const AS1 unsigned int*)(ab_ + go1 + kb_),       \
            (AS3 unsigned int*)(&sA[sl_][ldo1]), 16, 0, 0);                                \
    } while (0)
#define ISSUE_B(tt)                                                                        \
    do {                                                                                   \
        int sg_ = (tt) >= 96 ? 2 : ((tt) >= 48 ? 1 : 0);                                   \
        int kb_ = ((tt) - sg_ * 48) * (BKT * 2);                                           \
        const char* bb_ = (sg_ == 1) ? gBm : gBh;                                          \
        int sl_ = (tt) % 3;                                                                \
        __builtin_amdgcn_global_load_lds((const AS1 unsigned int*)(bb_ + go0 + kb_),       \
            (AS3 unsigned int*)(&sB[sl_][ldo0]), 16, 0, 0);                                \
        __builtin_amdgcn_global_load_lds((const AS1 unsigned int*)(bb_ + go1 + kb_),       \
            (AS3 unsigned int*)(&sB[sl_][ldo1]), 16, 0, 0);                                \
    } while (0)

    // prologue: stage tiles 0,1,2 (12 loads); wait tile 0 (leave 8 in flight)
    ISSUE_A(0); ISSUE_B(0);
    ISSUE_A(1); ISSUE_B(1);
    ISSUE_A(2); ISSUE_B(2);
    asm volatile("s_waitcnt vmcnt(8)" ::: "memory");
    __builtin_amdgcn_sched_barrier(0);
    __builtin_amdgcn_s_barrier();
    __builtin_amdgcn_sched_barrier(0);

    for (int T = 0; T < NTT; ++T) {
        int sl = T % 3;
        const _Float16* pA = sA[sl];
        const _Float16* pB = sB[sl];

        if (T == 96) {            // cross-sum done -> scale by 2^-11 (exact)
            #pragma unroll
            for (int mi = 0; mi < 8; ++mi)
                #pragma unroll
                for (int ni = 0; ni < 4; ++ni)
                    acc[mi][ni] *= (1.0f / 2048.0f);
        }

        f16x8 bf[4], af[4];
        // phase 1: B frags (held for both phases) + A mi0-3
        #pragma unroll
        for (int ni = 0; ni < 4; ++ni) {
            int ro = wn * 64 + ni * 16 + l15;
            bf[ni] = *(const f16x8*)&pB[ro * 32 + kswz];
        }
        #pragma unroll
        for (int mi = 0; mi < 4; ++mi) {
            int ro = wm * 128 + mi * 16 + l15;
            af[mi] = *(const f16x8*)&pA[ro * 32 + kswz];
        }
        if (T + 2 < NTT) ISSUE_A(T + 2);
        __builtin_amdgcn_s_setprio(1);
        #pragma unroll
        for (int mi = 0; mi < 4; ++mi)
            #pragma unroll
            for (int ni = 0; ni < 4; ++ni)
                acc[mi][ni] = mfma16(af[mi], bf[ni], acc[mi][ni]);
        __builtin_amdgcn_s_setprio(0);

        // phase 2: A mi4-7 (B reused)
        #pragma unroll
        for (int mi = 0; mi < 4; ++mi) {
            int ro = wm * 128 + (mi + 4) * 16 + l15;
            af[mi] = *(const f16x8*)&pA[ro * 32 + kswz];
        }
        if (T + 2 < NTT) ISSUE_B(T + 2);
        __builtin_amdgcn_s_setprio(1);
        #pragma unroll
        for (int mi = 0; mi < 4; ++mi)
            #pragma unroll
            for (int ni = 0; ni < 4; ++ni)
                acc[mi + 4][ni] = mfma16(af[mi], bf[ni], acc[mi + 4][ni]);
        __builtin_amdgcn_s_setprio(0);

        // tile boundary: T+1 must be landed; keep T+2's 4 loads in flight
        if (T < NTT - 2)
            asm volatile("s_waitcnt vmcnt(4)" ::: "memory");
        else
            asm volatile("s_waitcnt vmcnt(0)" ::: "memory");
        __builtin_amdgcn_sched_barrier(0);
        __builtin_amdgcn_s_barrier();
        __builtin_amdgcn_sched_barrier(0);
    }
#undef ISSUE_A
#undef ISSUE_B

    #pragma unroll
    for (int mi = 0; mi < 8; ++mi) {
        #pragma unroll
        for (int ni = 0; ni < 4; ++ni) {
            int colL = n0 + wn * 64 + ni * 16 + l15;
            #pragma unroll
            for (int rr = 0; rr < 4; ++rr) {
                int rowL = m0 + wm * 128 + mi * 16 + lg * 4 + rr;
                if (rowL < Mreal) {
                    int g = row0 + rowL;
                    float v = acc[mi][ni][rr]
                              + (1.0f + (float)counts[g]) * bias[colL];
                    out[(size_t)g * C_DIM + colL] = tanhf(v);
                }
            }
        }
    }
}

extern "C" void kernel_launch(void* const* d_in, const int* in_sizes, int n_in,
                              void* d_out, int out_size, void* d_ws, size_t ws_size,
                              hipStream_t stream) {
    const float* x    = (const float*)d_in[0];
    const float* Wt   = (const float*)d_in[1];
    const float* Wl   = (const float*)d_in[2];
    const float* Wr   = (const float*)d_in[3];
    const float* bias = (const float*)d_in[4];
    const int* parent = (const int*)d_in[5];
    const int* level  = (const int*)d_in[6];
    const int* pos    = (const int*)d_in[7];
    const int* sib    = (const int*)d_in[8];
    const int N = in_sizes[5];
    float* out = (float*)d_out;
    (void)n_in; (void)out_size;

    char* w = (char*)d_ws;
    size_t off = 0;
    auto alloc = [&](size_t bytes) -> void* {
        void* p = w + off;
        off += (bytes + 255) & ~(size_t)255;
        return p;
    };
    int* counts    = (int*)alloc((size_t)N * 4);
    int* starts    = (int*)alloc((size_t)N * 4);
    int* childlist = (int*)alloc((size_t)N * 4);
    int* bsums     = (int*)alloc(1024 * 4);
    _Float16* Bh   = (_Float16*)alloc((size_t)C_DIM * K3 * 2);
    _Float16* Bm   = (_Float16*)alloc((size_t)C_DIM * K3 * 2);

    size_t avail = ws_size > off ? ws_size - off : 0;
    long long Npad = ((long long)N + 255) & ~255LL;
    long long chunkM = (long long)(avail / ((size_t)K3 * 2 * 2)) & ~255LL;
    if (chunkM > Npad) chunkM = Npad;
    if (chunkM < 256) chunkM = 256;
    _Float16* Ah = (_Float16*)alloc((size_t)chunkM * K3 * 2);
    _Float16* Am = (_Float16*)alloc((size_t)chunkM * K3 * 2);

    hipMemsetAsync(counts, 0, (size_t)N * 4, stream);
    int nb256 = (N + 255) / 256;
    int nb1024 = (N + 1023) / 1024;
    k_count<<<nb256, 256, 0, stream>>>(parent, counts, N);
    k_scan1<<<nb1024, 1024, 0, stream>>>(counts, starts, bsums, N);
    k_scan2<<<1, 1024, 0, stream>>>(bsums, nb1024);
    k_scan3<<<nb1024, 1024, 0, stream>>>(starts, bsums, N);
    k_fill<<<nb256, 256, 0, stream>>>(parent, pos, starts, childlist, N);
    k_bcat<<<(C_DIM * K3 + 255) / 256, 256, 0, stream>>>(Wt, Wl, Wr, Bh, Bm);

    for (long long m0 = 0; m0 < N; m0 += chunkM) {
        int mc = (int)((N - m0 < chunkM) ? (N - m0) : chunkM);
        int mcPad = (mc + 255) & ~255;
        k_agg<<<2048, 256, 0, stream>>>(x, level, pos, sib, starts, counts, childlist,
                                        Ah, Am, (int)m0, mc);
        int ntiles = (mcPad / 256) * 2;
        k_gemm<<<ntiles, 512, 0, stream>>>(Ah, Am, Bh, Bm, bias, counts,
                                           out, mc, (int)m0);
    }
}

// Round 11
// 903.488 us; speedup vs baseline: 1.0107x; 1.0107x over previous
//
#include <hip/hip_runtime.h>
#include <hip/hip_bf16.h>
#include <stdint.h>

#define F_DIM 512
#define C_DIM 512
#define K3    1536   // 3 * F_DIM
#define NT    48     // K3 / 32  (BK = 32)

typedef _Float16 f16x8 __attribute__((ext_vector_type(8)));
typedef float    f32x4 __attribute__((ext_vector_type(4)));

__device__ __forceinline__ float rho_of(int p, int sb) {
    int d = sb - 1; if (d < 1) d = 1;
    return (float)(p - 1) / (float)d;
}

// 2-way fp16 split with exact pow2 plane scaling: v ~= h + m*2^-11
__device__ __forceinline__ void split2s(float v, _Float16& h, _Float16& m) {
    h = (_Float16)v;
    float r1 = v - (float)h;          // exact
    m = (_Float16)(r1 * 2048.0f);     // scale exact, one rounding
}

// ---------------- CSR build ----------------
__global__ void k_count(const int* __restrict__ parent, int* __restrict__ counts, int n) {
    int c = blockIdx.x * 256 + threadIdx.x;
    if (c >= 1 && c < n) atomicAdd(&counts[parent[c]], 1);
}

__device__ __forceinline__ int blockScanIncl(int v, int* sm) {
    int lane = threadIdx.x & 63;
    int w = threadIdx.x >> 6;
    #pragma unroll
    for (int d = 1; d < 64; d <<= 1) {
        int t = __shfl_up(v, d, 64);
        if (lane >= d) v += t;
    }
    if (lane == 63) sm[w] = v;
    __syncthreads();
    if (threadIdx.x < 64) {
        int s = (threadIdx.x < 16) ? sm[threadIdx.x] : 0;
        #pragma unroll
        for (int d = 1; d < 16; d <<= 1) {
            int t = __shfl_up(s, d, 64);
            if (lane >= d) s += t;
        }
        if (threadIdx.x < 16) sm[threadIdx.x] = s;
    }
    __syncthreads();
    return v + (w > 0 ? sm[w - 1] : 0);
}

__global__ void k_scan1(const int* __restrict__ counts, int* __restrict__ starts,
                        int* __restrict__ bsums, int n) {
    __shared__ int sm[16];
    int i = blockIdx.x * 1024 + threadIdx.x;
    int v = (i < n) ? counts[i] : 0;
    int incl = blockScanIncl(v, sm);
    if (i < n) starts[i] = incl - v;
    if (threadIdx.x == 1023) bsums[blockIdx.x] = incl;
}

__global__ void k_scan2(int* __restrict__ bsums, int nb) {
    __shared__ int sm[16];
    int v = ((int)threadIdx.x < nb) ? bsums[threadIdx.x] : 0;
    int incl = blockScanIncl(v, sm);
    if ((int)threadIdx.x < nb) bsums[threadIdx.x] = incl - v;  // exclusive
}

__global__ void k_scan3(int* __restrict__ starts, const int* __restrict__ bsums, int n) {
    int i = blockIdx.x * 1024 + threadIdx.x;
    if (i < n) starts[i] += bsums[blockIdx.x];
}

__global__ void k_fill(const int* __restrict__ parent, const int* __restrict__ pos,
                       const int* __restrict__ starts, int* __restrict__ childlist, int n) {
    int c = blockIdx.x * 256 + threadIdx.x;
    if (c >= 1 && c < n) childlist[starts[parent[c]] + pos[c]] = c;
}

// ---------------- B concat + 2-way split:  B[j][sec*512+f], sec: 0=Wt 1=Wl 2=Wr
__global__ void k_bcat(const float* __restrict__ Wt, const float* __restrict__ Wl,
                       const float* __restrict__ Wr,
                       _Float16* __restrict__ Bh, _Float16* __restrict__ Bm) {
    int i = blockIdx.x * 256 + threadIdx.x;
    if (i >= C_DIM * K3) return;
    int j = i / K3, kk = i - j * K3;
    int sec = kk >> 9, f = kk & 511;
    const float* W = (sec == 0) ? Wt : ((sec == 1) ? Wl : Wr);
    float v = W[j * F_DIM + f];
    _Float16 h, m;
    split2s(v, h, m);
    Bh[i] = h; Bm[i] = m;
}

// ---------------- aggregation: one wave per node.
__global__ __launch_bounds__(256)
void k_agg(const float* __restrict__ x, const int* __restrict__ level,
           const int* __restrict__ pos, const int* __restrict__ sib,
           const int* __restrict__ starts, const int* __restrict__ counts,
           const int* __restrict__ childlist,
           _Float16* __restrict__ Ah, _Float16* __restrict__ Am,
           int node0, int cnt) {
    int lane = threadIdx.x & 63;
    int gw = (blockIdx.x * 256 + threadIdx.x) >> 6;
    int nW = (gridDim.x * 256) >> 6;
    for (int i = gw; i < cnt; i += nW) {
        int s = node0 + i;
        float t = 0.5f * (float)level[s];
        float u = 1.0f - t;
        float u2 = u * u;
        float s0[8], s1[8];
        #pragma unroll
        for (int j = 0; j < 8; ++j) { s0[j] = 0.f; s1[j] = 0.f; }
        {
            float r = rho_of(pos[s], sib[s]);
            const float4* xp = (const float4*)(x + (size_t)s * F_DIM) + lane * 2;
            float4 a = xp[0], b = xp[1];
            float vv[8] = {a.x, a.y, a.z, a.w, b.x, b.y, b.z, b.w};
            #pragma unroll
            for (int j = 0; j < 8; ++j) { s0[j] += vv[j]; s1[j] = fmaf(r, vv[j], s1[j]); }
        }
        int cs = starts[s], ne = counts[s];
        for (int e = 0; e < ne; ++e) {
            int c = childlist[cs + e];
            float r = rho_of(pos[c], sib[c]);
            const float4* xp = (const float4*)(x + (size_t)c * F_DIM) + lane * 2;
            float4 a = xp[0], b = xp[1];
            float vv[8] = {a.x, a.y, a.z, a.w, b.x, b.y, b.z, b.w};
            #pragma unroll
            for (int j = 0; j < 8; ++j) { s0[j] += vv[j]; s1[j] = fmaf(r, vv[j], s1[j]); }
        }
        f16x8 ph[3], pm[3];
        #pragma unroll
        for (int j = 0; j < 8; ++j) {
            float a0 = t * s0[j];
            float a1 = fmaf(-u2, s1[j], u * s0[j]);
            float a2 = u * s1[j];
            _Float16 h, m;
            split2s(a0, h, m); ph[0][j] = h; pm[0][j] = m;
            split2s(a1, h, m); ph[1][j] = h; pm[1][j] = m;
            split2s(a2, h, m); ph[2][j] = h; pm[2][j] = m;
        }
        size_t rb = (size_t)i * K3 + (size_t)(lane * 8);
        #pragma unroll
        for (int sec = 0; sec < 3; ++sec) {
            *(f16x8*)(Ah + rb + sec * 512) = ph[sec];
            *(f16x8*)(Am + rb + sec * 512) = pm[sec];
        }
    }
}

// ---------------- GEMM: out = tanh(A(M x 1536) * Bcat^T + (1+nc)*bias)
// fp16 2-plane, 3 products (hh -> accH; hm+mh -> accR, scale 2^-11).
// 256 threads = 4 waves (2x2), wave tile 64x64 (min LDS-read traffic),
// block tile 128x128, BK=32 DOUBLE-BUFFER: 4 planes x 2 x 8KB = 64KB
// -> 2 blocks/CU preserved (acc 128 AGPR + ~110 VGPR = 2 waves/SIMD).
// Catalog-minimum 2-phase recipe (m248v2): per tile
//   { STAGE(buf^1, t+1) issue FIRST; frag ds_reads from buf; 48 MFMA;
//     __syncthreads() }                     <- ONE barrier per tile;
// its vmcnt(0) drain lands after MFMA has covered the load latency.
// (R8's failure ingredients removed: 2nd barrier, sched_barrier pins,
//  pre-compute vmcnt wait.)
// BK=32 LDS XOR swizzle (R8 HW-verified: 0 conflicts, correct output):
// slot' = slot ^ ((row>>1)&3), inverse on global SOURCE (linear LDS dest
// per rule #21), same XOR on the ds_read address.
__device__ __forceinline__ f32x4 mfma16(f16x8 a, f16x8 b, f32x4 c) {
    return __builtin_amdgcn_mfma_f32_16x16x32_f16(a, b, c, 0, 0, 0);
}

#define AS1 __attribute__((address_space(1)))
#define AS3 __attribute__((address_space(3)))

__global__ __launch_bounds__(256, 2)
void k_gemm(const _Float16* __restrict__ Ah, const _Float16* __restrict__ Am,
            const _Float16* __restrict__ Bh, const _Float16* __restrict__ Bm,
            const float* __restrict__ bias, const int* __restrict__ counts,
            float* __restrict__ out, int Mreal, int row0) {
    // [2 dbuf][128 rows][32 elems] per plane, 8KB per buf
    __shared__ __align__(16) _Float16 sAh[2][128 * 32];
    __shared__ __align__(16) _Float16 sAm[2][128 * 32];
    __shared__ __align__(16) _Float16 sBh[2][128 * 32];
    __shared__ __align__(16) _Float16 sBm[2][128 * 32];

    // bijective XCD swizzle (m204); 4 col-tiles of an M-panel share an XCD
    int nwg = gridDim.x, bid = blockIdx.x;
    int q = nwg >> 3, r = nwg & 7;
    int xcd = bid & 7, idx = bid >> 3;
    int wg = (xcd < r ? xcd * (q + 1) : r * (q + 1) + (xcd - r) * q) + idx;
    int panel = wg >> 2, colt = wg & 3;
    int m0 = panel * 128, n0 = colt * 128;

    int tid = threadIdx.x;
    int lane = tid & 63, wid = tid >> 6;
    int wm = wid >> 1, wn = wid & 1;
    int l15 = lane & 15, lg = lane >> 4;

    // staging source offsets: per plane [128 rows][4 slots of 16B] = 512 chunks;
    // thread handles chunks tid and 256+tid; source slot inverse-swizzled.
    int c0 = tid,       r0 = c0 >> 2, s0g = (c0 & 3) ^ ((r0 >> 1) & 3);
    int c1 = 256 + tid, r1 = c1 >> 2, s1g = (c1 & 3) ^ ((r1 >> 1) & 3);
    size_t so0 = (size_t)r0 * (K3 * 2) + (size_t)(s0g << 4);
    size_t so1 = (size_t)r1 * (K3 * 2) + (size_t)(s1g << 4);
    const char* gAh0 = (const char*)(Ah + (size_t)m0 * K3) + so0;
    const char* gAh1 = (const char*)(Ah + (size_t)m0 * K3) + so1;
    const char* gAm0 = (const char*)(Am + (size_t)m0 * K3) + so0;
    const char* gAm1 = (const char*)(Am + (size_t)m0 * K3) + so1;
    const char* gBh0 = (const char*)(Bh + (size_t)n0 * K3) + so0;
    const char* gBh1 = (const char*)(Bh + (size_t)n0 * K3) + so1;
    const char* gBm0 = (const char*)(Bm + (size_t)n0 * K3) + so0;
    const char* gBm1 = (const char*)(Bm + (size_t)n0 * K3) + so1;
    // linear LDS dest (wave-uniform base; HW adds lane*16B)
    int ld0 = (0 * 256 + wid * 64) * 8;
    int ld1 = (1 * 256 + wid * 64) * 8;

    // ds_read swizzled k-slot (element offset): slot' = lg ^ ((l15>>1)&3)
    int koff = ((lg ^ ((l15 >> 1) & 3)) << 3);

    f32x4 accH[4][4] = {};
    f32x4 accR[4][4] = {};

#define STAGE(pb, kb)                                                                      \
    do {                                                                                   \
        __builtin_amdgcn_global_load_lds((const AS1 unsigned int*)(gAh0 + (kb)),           \
            (AS3 unsigned int*)(&sAh[pb][ld0]), 16, 0, 0);                                 \
        __builtin_amdgcn_global_load_lds((const AS1 unsigned int*)(gAh1 + (kb)),           \
            (AS3 unsigned int*)(&sAh[pb][ld1]), 16, 0, 0);                                 \
        __builtin_amdgcn_global_load_lds((const AS1 unsigned int*)(gAm0 + (kb)),           \
            (AS3 unsigned int*)(&sAm[pb][ld0]), 16, 0, 0);                                 \
        __builtin_amdgcn_global_load_lds((const AS1 unsigned int*)(gAm1 + (kb)),           \
            (AS3 unsigned int*)(&sAm[pb][ld1]), 16, 0, 0);                                 \
        __builtin_amdgcn_global_load_lds((const AS1 unsigned int*)(gBh0 + (kb)),           \
            (AS3 unsigned int*)(&sBh[pb][ld0]), 16, 0, 0);                                 \
        __builtin_amdgcn_global_load_lds((const AS1 unsigned int*)(gBh1 + (kb)),           \
            (AS3 unsigned int*)(&sBh[pb][ld1]), 16, 0, 0);                                 \
        __builtin_amdgcn_global_load_lds((const AS1 unsigned int*)(gBm0 + (kb)),           \
            (AS3 unsigned int*)(&sBm[pb][ld0]), 16, 0, 0);                                 \
        __builtin_amdgcn_global_load_lds((const AS1 unsigned int*)(gBm1 + (kb)),           \
            (AS3 unsigned int*)(&sBm[pb][ld1]), 16, 0, 0);                                 \
    } while (0)

    // prologue: stage tile 0 into buf 0; full drain + barrier
    STAGE(0, 0);
    __syncthreads();

    for (int t = 0; t < NT; ++t) {
        int p = t & 1;
        if (t + 1 < NT) STAGE(p ^ 1, (size_t)(t + 1) * 64);   // issue FIRST

        f16x8 ah[4], am[4], bh[4], bm[4];
        #pragma unroll
        for (int ni = 0; ni < 4; ++ni) {
            int co = (wn * 64 + ni * 16 + l15) * 32 + koff;
            bh[ni] = *(const f16x8*)&sBh[p][co];
            bm[ni] = *(const f16x8*)&sBm[p][co];
        }
        #pragma unroll
        for (int mi = 0; mi < 4; ++mi) {
            int ro = (wm * 64 + mi * 16 + l15) * 32 + koff;
            ah[mi] = *(const f16x8*)&sAh[p][ro];
            am[mi] = *(const f16x8*)&sAm[p][ro];
        }
        #pragma unroll
        for (int mi = 0; mi < 4; ++mi) {
            #pragma unroll
            for (int ni = 0; ni < 4; ++ni) {
                accH[mi][ni] = mfma16(ah[mi], bh[ni], accH[mi][ni]);
                accR[mi][ni] = mfma16(ah[mi], bm[ni], accR[mi][ni]);
                accR[mi][ni] = mfma16(am[mi], bh[ni], accR[mi][ni]);
            }
        }
        __syncthreads();   // one barrier/tile: drains t+1 loads (covered by MFMA)
    }
#undef STAGE

    const float S1 = 1.0f / 2048.0f;        // 2^-11

    #pragma unroll
    for (int mi = 0; mi < 4; ++mi) {
        #pragma unroll
        for (int ni = 0; ni < 4; ++ni) {
            int colL = n0 + wn * 64 + ni * 16 + l15;
            #pragma unroll
            for (int rr = 0; rr < 4; ++rr) {
                int rowL = m0 + wm * 64 + mi * 16 + lg * 4 + rr;
                if (rowL < Mreal) {
                    int g = row0 + rowL;
                    float v = accH[mi][ni][rr]
                              + accR[mi][ni][rr] * S1
                              + (1.0f + (float)counts[g]) * bias[colL];
                    out[(size_t)g * C_DIM + colL] = tanhf(v);
                }
            }
        }
    }
}

extern "C" void kernel_launch(void* const* d_in, const int* in_sizes, int n_in,
                              void* d_out, int out_size, void* d_ws, size_t ws_size,
                              hipStream_t stream) {
    const float* x    = (const float*)d_in[0];
    const float* Wt   = (const float*)d_in[1];
    const float* Wl   = (const float*)d_in[2];
    const float* Wr   = (const float*)d_in[3];
    const float* bias = (const float*)d_in[4];
    const int* parent = (const int*)d_in[5];
    const int* level  = (const int*)d_in[6];
    const int* pos    = (const int*)d_in[7];
    const int* sib    = (const int*)d_in[8];
    const int N = in_sizes[5];
    float* out = (float*)d_out;
    (void)n_in; (void)out_size;

    char* w = (char*)d_ws;
    size_t off = 0;
    auto alloc = [&](size_t bytes) -> void* {
        void* p = w + off;
        off += (bytes + 255) & ~(size_t)255;
        return p;
    };
    int* counts    = (int*)alloc((size_t)N * 4);
    int* starts    = (int*)alloc((size_t)N * 4);
    int* childlist = (int*)alloc((size_t)N * 4);
    int* bsums     = (int*)alloc(1024 * 4);
    _Float16* Bh   = (_Float16*)alloc((size_t)C_DIM * K3 * 2);
    _Float16* Bm   = (_Float16*)alloc((size_t)C_DIM * K3 * 2);

    size_t avail = ws_size > off ? ws_size - off : 0;
    long long Npad = ((long long)N + 127) & ~127LL;
    long long chunkM = (long long)(avail / ((size_t)K3 * 2 * 2)) & ~127LL;
    if (chunkM > Npad) chunkM = Npad;
    if (chunkM < 128) chunkM = 128;
    _Float16* Ah = (_Float16*)alloc((size_t)chunkM * K3 * 2);
    _Float16* Am = (_Float16*)alloc((size_t)chunkM * K3 * 2);

    hipMemsetAsync(counts, 0, (size_t)N * 4, stream);
    int nb256 = (N + 255) / 256;
    int nb1024 = (N + 1023) / 1024;
    k_count<<<nb256, 256, 0, stream>>>(parent, counts, N);
    k_scan1<<<nb1024, 1024, 0, stream>>>(counts, starts, bsums, N);
    k_scan2<<<1, 1024, 0, stream>>>(bsums, nb1024);
    k_scan3<<<nb1024, 1024, 0, stream>>>(starts, bsums, N);
    k_fill<<<nb256, 256, 0, stream>>>(parent, pos, starts, childlist, N);
    k_bcat<<<(C_DIM * K3 + 255) / 256, 256, 0, stream>>>(Wt, Wl, Wr, Bh, Bm);

    for (long long m0 = 0; m0 < N; m0 += chunkM) {
        int mc = (int)((N - m0 < chunkM) ? (N - m0) : chunkM);
        int mcPad = (mc + 127) & ~127;
        k_agg<<<2048, 256, 0, stream>>>(x, level, pos, sib, starts, counts, childlist,
                                        Ah, Am, (int)m0, mc);
        int ntiles = (mcPad / 128) * 4;
        k_gemm<<<ntiles, 256, 0, stream>>>(Ah, Am, Bh, Bm, bias, counts,
                                           out, mc, (int)m0);
    }
}

// Round 12
// 796.574 us; speedup vs baseline: 1.1463x; 1.1342x over previous
//
#include <hip/hip_runtime.h>
#include <hip/hip_bf16.h>
#include <stdint.h>

#define F_DIM 512
#define C_DIM 512
#define K3    1536   // 3 * F_DIM
#define NT    24     // K3 / 64

typedef _Float16 f16x8  __attribute__((ext_vector_type(8)));
typedef float    f32x16 __attribute__((ext_vector_type(16)));

__device__ __forceinline__ float rho_of(int p, int sb) {
    int d = sb - 1; if (d < 1) d = 1;
    return (float)(p - 1) / (float)d;
}

// 2-way fp16 split with exact pow2 plane scaling: v ~= h + m*2^-11
__device__ __forceinline__ void split2s(float v, _Float16& h, _Float16& m) {
    h = (_Float16)v;
    float r1 = v - (float)h;          // exact
    m = (_Float16)(r1 * 2048.0f);     // scale exact, one rounding
}

// ---------------- CSR build ----------------
__global__ void k_count(const int* __restrict__ parent, int* __restrict__ counts, int n) {
    int c = blockIdx.x * 256 + threadIdx.x;
    if (c >= 1 && c < n) atomicAdd(&counts[parent[c]], 1);
}

__device__ __forceinline__ int blockScanIncl(int v, int* sm) {
    int lane = threadIdx.x & 63;
    int w = threadIdx.x >> 6;
    #pragma unroll
    for (int d = 1; d < 64; d <<= 1) {
        int t = __shfl_up(v, d, 64);
        if (lane >= d) v += t;
    }
    if (lane == 63) sm[w] = v;
    __syncthreads();
    if (threadIdx.x < 64) {
        int s = (threadIdx.x < 16) ? sm[threadIdx.x] : 0;
        #pragma unroll
        for (int d = 1; d < 16; d <<= 1) {
            int t = __shfl_up(s, d, 64);
            if (lane >= d) s += t;
        }
        if (threadIdx.x < 16) sm[threadIdx.x] = s;
    }
    __syncthreads();
    return v + (w > 0 ? sm[w - 1] : 0);
}

__global__ void k_scan1(const int* __restrict__ counts, int* __restrict__ starts,
                        int* __restrict__ bsums, int n) {
    __shared__ int sm[16];
    int i = blockIdx.x * 1024 + threadIdx.x;
    int v = (i < n) ? counts[i] : 0;
    int incl = blockScanIncl(v, sm);
    if (i < n) starts[i] = incl - v;
    if (threadIdx.x == 1023) bsums[blockIdx.x] = incl;
}

__global__ void k_scan2(int* __restrict__ bsums, int nb) {
    __shared__ int sm[16];
    int v = ((int)threadIdx.x < nb) ? bsums[threadIdx.x] : 0;
    int incl = blockScanIncl(v, sm);
    if ((int)threadIdx.x < nb) bsums[threadIdx.x] = incl - v;  // exclusive
}

__global__ void k_scan3(int* __restrict__ starts, const int* __restrict__ bsums, int n) {
    int i = blockIdx.x * 1024 + threadIdx.x;
    if (i < n) starts[i] += bsums[blockIdx.x];
}

__global__ void k_fill(const int* __restrict__ parent, const int* __restrict__ pos,
                       const int* __restrict__ starts, int* __restrict__ childlist, int n) {
    int c = blockIdx.x * 256 + threadIdx.x;
    if (c >= 1 && c < n) childlist[starts[parent[c]] + pos[c]] = c;
}

// ---------------- B concat + 2-way split:  B[j][sec*512+f], sec: 0=Wt 1=Wl 2=Wr
__global__ void k_bcat(const float* __restrict__ Wt, const float* __restrict__ Wl,
                       const float* __restrict__ Wr,
                       _Float16* __restrict__ Bh, _Float16* __restrict__ Bm) {
    int i = blockIdx.x * 256 + threadIdx.x;
    if (i >= C_DIM * K3) return;
    int j = i / K3, kk = i - j * K3;
    int sec = kk >> 9, f = kk & 511;
    const float* W = (sec == 0) ? Wt : ((sec == 1) ? Wl : Wr);
    float v = W[j * F_DIM + f];
    _Float16 h, m;
    split2s(v, h, m);
    Bh[i] = h; Bm[i] = m;
}

// ---------------- aggregation: one wave per node.
__global__ __launch_bounds__(256)
void k_agg(const float* __restrict__ x, const int* __restrict__ level,
           const int* __restrict__ pos, const int* __restrict__ sib,
           const int* __restrict__ starts, const int* __restrict__ counts,
           const int* __restrict__ childlist,
           _Float16* __restrict__ Ah, _Float16* __restrict__ Am,
           int node0, int cnt) {
    int lane = threadIdx.x & 63;
    int gw = (blockIdx.x * 256 + threadIdx.x) >> 6;
    int nW = (gridDim.x * 256) >> 6;
    for (int i = gw; i < cnt; i += nW) {
        int s = node0 + i;
        float t = 0.5f * (float)level[s];
        float u = 1.0f - t;
        float u2 = u * u;
        float s0[8], s1[8];
        #pragma unroll
        for (int j = 0; j < 8; ++j) { s0[j] = 0.f; s1[j] = 0.f; }
        {
            float r = rho_of(pos[s], sib[s]);
            const float4* xp = (const float4*)(x + (size_t)s * F_DIM) + lane * 2;
            float4 a = xp[0], b = xp[1];
            float vv[8] = {a.x, a.y, a.z, a.w, b.x, b.y, b.z, b.w};
            #pragma unroll
            for (int j = 0; j < 8; ++j) { s0[j] += vv[j]; s1[j] = fmaf(r, vv[j], s1[j]); }
        }
        int cs = starts[s], ne = counts[s];
        for (int e = 0; e < ne; ++e) {
            int c = childlist[cs + e];
            float r = rho_of(pos[c], sib[c]);
            const float4* xp = (const float4*)(x + (size_t)c * F_DIM) + lane * 2;
            float4 a = xp[0], b = xp[1];
            float vv[8] = {a.x, a.y, a.z, a.w, b.x, b.y, b.z, b.w};
            #pragma unroll
            for (int j = 0; j < 8; ++j) { s0[j] += vv[j]; s1[j] = fmaf(r, vv[j], s1[j]); }
        }
        f16x8 ph[3], pm[3];
        #pragma unroll
        for (int j = 0; j < 8; ++j) {
            float a0 = t * s0[j];
            float a1 = fmaf(-u2, s1[j], u * s0[j]);
            float a2 = u * s1[j];
            _Float16 h, m;
            split2s(a0, h, m); ph[0][j] = h; pm[0][j] = m;
            split2s(a1, h, m); ph[1][j] = h; pm[1][j] = m;
            split2s(a2, h, m); ph[2][j] = h; pm[2][j] = m;
        }
        size_t rb = (size_t)i * K3 + (size_t)(lane * 8);
        #pragma unroll
        for (int sec = 0; sec < 3; ++sec) {
            *(f16x8*)(Ah + rb + sec * 512) = ph[sec];
            *(f16x8*)(Am + rb + sec * 512) = pm[sec];
        }
    }
}

// ---------------- GEMM: out = tanh(A(M x 1536) * Bcat^T + (1+nc)*bias)
// fp16 2-plane, 3 products (hh -> accH; hm+mh -> accR, scale 2^-11).
// R7 skeleton UNCHANGED (proven best of 5 schedule variants): 256 thr =
// 4 waves (2x2), wave tile 64x64, block tile 128x128, BK=64 SINGLE-buffer,
// stage -> sync -> compute -> sync, 2 blocks/CU (m114 implicit overlap).
// ONLY change: MFMA core 16x16x32 -> 32x32x16 (same FLOPs, ~8.07 vs
// 2x4.85 cyc per K=32 per tile-quad -> -17% matrix-pipe cycles, half the
// MFMA instruction count in the hot loop).
// Frag read (32x32x16): lane reads 8 consecutive k at row lane&31,
// k-chunk = ks*16 + (lane>>5)*8; swizzled slot = (ks*2+(lane>>5)) ^
// ((lane&31)&7). Bank audit: 8 slot-quads x 8 lanes = uniform -> 0 conflicts.
// Storage swizzle identical to R7 (slot^(row&7) inverse on global source).
// C/D layout (m74/m101-verified): col=lane&31, row=(reg&3)+8*(reg>>2)+4*(lane>>5).
__device__ __forceinline__ f32x16 mfma32(f16x8 a, f16x8 b, f32x16 c) {
    return __builtin_amdgcn_mfma_f32_32x32x16_f16(a, b, c, 0, 0, 0);
}

__device__ __forceinline__ void stageTile(const char* gbase, _Float16* lds) {
    int tid = threadIdx.x;
    int wid = tid >> 6;
    #pragma unroll
    for (int rnd = 0; rnd < 4; ++rnd) {
        int c = rnd * 256 + tid;          // 16B chunk id within [128 rows][8 slots]
        int row = c >> 3;
        int gslot = (c & 7) ^ (row & 7);  // inverse swizzle on the SOURCE
        const void* gp = gbase + (size_t)row * (K3 * 2) + ((size_t)gslot << 4);
        _Float16* lp = lds + (size_t)(rnd * 256 + wid * 64) * 8;  // wave-uniform base
        __builtin_amdgcn_global_load_lds(
            (const __attribute__((address_space(1))) unsigned int*)gp,
            (__attribute__((address_space(3))) unsigned int*)lp, 16, 0, 0);
    }
}

__global__ __launch_bounds__(256, 2)
void k_gemm(const _Float16* __restrict__ Ah, const _Float16* __restrict__ Am,
            const _Float16* __restrict__ Bh, const _Float16* __restrict__ Bm,
            const float* __restrict__ bias, const int* __restrict__ counts,
            float* __restrict__ out, int Mreal, int row0) {
    __shared__ __align__(16) _Float16 sAh[128 * 64];
    __shared__ __align__(16) _Float16 sAm[128 * 64];
    __shared__ __align__(16) _Float16 sBh[128 * 64];
    __shared__ __align__(16) _Float16 sBm[128 * 64];

    // bijective XCD swizzle (m204); 4 col-tiles of an M-panel share an XCD
    int nwg = gridDim.x, bid = blockIdx.x;
    int q = nwg >> 3, r = nwg & 7;
    int xcd = bid & 7, idx = bid >> 3;
    int wg = (xcd < r ? xcd * (q + 1) : r * (q + 1) + (xcd - r) * q) + idx;
    int panel = wg >> 2, colt = wg & 3;
    int m0 = panel * 128, n0 = colt * 128;

    int tid = threadIdx.x;
    int lane = tid & 63, wid = tid >> 6;
    int wm = wid >> 1, wn = wid & 1;
    int l31 = lane & 31, lg5 = lane >> 5, lx7 = l31 & 7;

    const char* gAh = (const char*)(Ah + (size_t)m0 * K3);
    const char* gAm = (const char*)(Am + (size_t)m0 * K3);
    const char* gBh = (const char*)(Bh + (size_t)n0 * K3);
    const char* gBm = (const char*)(Bm + (size_t)n0 * K3);

    f32x16 accH[2][2] = {};
    f32x16 accR[2][2] = {};

    // swizzled k-element offsets per kstep: slot = (ks*2 + lg5) ^ lx7
    int koffs[4];
    #pragma unroll
    for (int ks = 0; ks < 4; ++ks) koffs[ks] = (((ks * 2 + lg5) ^ lx7) << 3);

    for (int t = 0; t < NT; ++t) {
        size_t kb = (size_t)t * 128;     // 64 elems * 2B along K
        stageTile(gAh + kb, sAh); stageTile(gAm + kb, sAm);
        stageTile(gBh + kb, sBh); stageTile(gBm + kb, sBm);
        __syncthreads();                 // drain hidden by co-resident block

        #pragma unroll
        for (int ks = 0; ks < 4; ++ks) {
            int ko = koffs[ks];
            f16x8 ah[2], am[2], bh[2], bm[2];
            #pragma unroll
            for (int nt = 0; nt < 2; ++nt) {
                int co = (wn * 64 + nt * 32 + l31) * 64 + ko;
                bh[nt] = *(const f16x8*)&sBh[co];
                bm[nt] = *(const f16x8*)&sBm[co];
            }
            #pragma unroll
            for (int mt = 0; mt < 2; ++mt) {
                int ro = (wm * 64 + mt * 32 + l31) * 64 + ko;
                ah[mt] = *(const f16x8*)&sAh[ro];
                am[mt] = *(const f16x8*)&sAm[ro];
            }
            #pragma unroll
            for (int mt = 0; mt < 2; ++mt) {
                #pragma unroll
                for (int nt = 0; nt < 2; ++nt) {
                    accH[mt][nt] = mfma32(ah[mt], bh[nt], accH[mt][nt]);
                    accR[mt][nt] = mfma32(ah[mt], bm[nt], accR[mt][nt]);
                    accR[mt][nt] = mfma32(am[mt], bh[nt], accR[mt][nt]);
                }
            }
        }
        __syncthreads();                 // reads done -> safe to overwrite
    }

    const float S1 = 1.0f / 2048.0f;        // 2^-11

    // C/D 32x32 mapping: col = lane&31, row = (reg&3) + 8*(reg>>2) + 4*(lane>>5)
    #pragma unroll
    for (int mt = 0; mt < 2; ++mt) {
        #pragma unroll
        for (int nt = 0; nt < 2; ++nt) {
            int colL = n0 + wn * 64 + nt * 32 + l31;
            float bcol = bias[colL];
            #pragma unroll
            for (int rr = 0; rr < 16; ++rr) {
                int rowL = m0 + wm * 64 + mt * 32 + (rr & 3) + 8 * (rr >> 2) + 4 * lg5;
                if (rowL < Mreal) {
                    int g = row0 + rowL;
                    float v = accH[mt][nt][rr]
                              + accR[mt][nt][rr] * S1
                              + (1.0f + (float)counts[g]) * bcol;
                    out[(size_t)g * C_DIM + colL] = tanhf(v);
                }
            }
        }
    }
}

extern "C" void kernel_launch(void* const* d_in, const int* in_sizes, int n_in,
                              void* d_out, int out_size, void* d_ws, size_t ws_size,
                              hipStream_t stream) {
    const float* x    = (const float*)d_in[0];
    const float* Wt   = (const float*)d_in[1];
    const float* Wl   = (const float*)d_in[2];
    const float* Wr   = (const float*)d_in[3];
    const float* bias = (const float*)d_in[4];
    const int* parent = (const int*)d_in[5];
    const int* level  = (const int*)d_in[6];
    const int* pos    = (const int*)d_in[7];
    const int* sib    = (const int*)d_in[8];
    const int N = in_sizes[5];
    float* out = (float*)d_out;
    (void)n_in; (void)out_size;

    char* w = (char*)d_ws;
    size_t off = 0;
    auto alloc = [&](size_t bytes) -> void* {
        void* p = w + off;
        off += (bytes + 255) & ~(size_t)255;
        return p;
    };
    int* counts    = (int*)alloc((size_t)N * 4);
    int* starts    = (int*)alloc((size_t)N * 4);
    int* childlist = (int*)alloc((size_t)N * 4);
    int* bsums     = (int*)alloc(1024 * 4);
    _Float16* Bh   = (_Float16*)alloc((size_t)C_DIM * K3 * 2);
    _Float16* Bm   = (_Float16*)alloc((size_t)C_DIM * K3 * 2);

    size_t avail = ws_size > off ? ws_size - off : 0;
    long long Npad = ((long long)N + 127) & ~127LL;
    long long chunkM = (long long)(avail / ((size_t)K3 * 2 * 2)) & ~127LL;
    if (chunkM > Npad) chunkM = Npad;
    if (chunkM < 128) chunkM = 128;
    _Float16* Ah = (_Float16*)alloc((size_t)chunkM * K3 * 2);
    _Float16* Am = (_Float16*)alloc((size_t)chunkM * K3 * 2);

    hipMemsetAsync(counts, 0, (size_t)N * 4, stream);
    int nb256 = (N + 255) / 256;
    int nb1024 = (N + 1023) / 1024;
    k_count<<<nb256, 256, 0, stream>>>(parent, counts, N);
    k_scan1<<<nb1024, 1024, 0, stream>>>(counts, starts, bsums, N);
    k_scan2<<<1, 1024, 0, stream>>>(bsums, nb1024);
    k_scan3<<<nb1024, 1024, 0, stream>>>(starts, bsums, N);
    k_fill<<<nb256, 256, 0, stream>>>(parent, pos, starts, childlist, N);
    k_bcat<<<(C_DIM * K3 + 255) / 256, 256, 0, stream>>>(Wt, Wl, Wr, Bh, Bm);

    for (long long m0 = 0; m0 < N; m0 += chunkM) {
        int mc = (int)((N - m0 < chunkM) ? (N - m0) : chunkM);
        int mcPad = (mc + 127) & ~127;
        k_agg<<<2048, 256, 0, stream>>>(x, level, pos, sib, starts, counts, childlist,
                                        Ah, Am, (int)m0, mc);
        int ntiles = (mcPad / 128) * 4;
        k_gemm<<<ntiles, 256, 0, stream>>>(Ah, Am, Bh, Bm, bias, counts,
                                           out, mc, (int)m0);
    }
}